// Round 3
// baseline (764.237 us; speedup 1.0000x reference)
//
#include <hip/hip_runtime.h>
#include <hip/hip_fp16.h>

// Fused MSE + SSIM loss, 32x3x512x512 fp32, MI355X.
// R2 structure: no input staging (global->reg horizontal pass), single LDS
// array for horizontal-pass results (fp16 pairs), conflict-free vertical pass,
// rcp for SSIM divide, last-block finalize (no second kernel).
// Tile 64(W) x 32(H), 256 threads, grid 8x16x96 = 12288 blocks.
// LDS = 5 fields * 42 rows * 32 half2 * 4B = 26.9 KB -> 5 blocks/CU.

#define WSZ   512
#define TW    64
#define TH    32
#define HALO  5
#define IN_H  (TH + 2*HALO)    // 42 rows of horizontal-pass output
#define HPW   32               // half2 pairs per row (64 px)
#define FS    (IN_H * HPW)     // 1344 floats per field
#define GX    8
#define GY    16
#define SSIM_C1 0.0001f
#define SSIM_C2 0.0009f

// 11-tap gaussian, sigma=1.5, normalized (f64-accurate literals)
#define W0 0.00102838f
#define W1 0.00759876f
#define W2 0.03600080f
#define W3 0.10936080f
#define W4 0.21300560f
#define W5 0.26601170f
__device__ __constant__ const float GW[11] = {W0,W1,W2,W3,W4,W5,W4,W3,W2,W1,W0};

// v_cvt_pkrtz_f16_f32: pack two fp32 -> fp16x2 in one instruction
static __device__ __forceinline__ float pkh2(float a, float b) {
    return __builtin_bit_cast(float, __builtin_amdgcn_cvt_pkrtz(a, b));
}

__launch_bounds__(256, 5)
__global__ void fused_mse_ssim(const float* __restrict__ P,
                               const float* __restrict__ T,
                               float* __restrict__ out,
                               float* __restrict__ ws,
                               float invN, int nblk) {
    __shared__ float sHP[5 * FS];
    __shared__ float red[2][4];

    const int tid = threadIdx.x;
    const int gx0 = blockIdx.x * TW;
    const int gy0 = blockIdx.y * TH;
    const size_t plane = (size_t)blockIdx.z * (WSZ * (size_t)WSZ);
    const float* Pp = P + plane;
    const float* Tp = T + plane;

    // weights as registers (compile-time floats; stage-B half2 copies)
    float gw[11];
    #pragma unroll
    for (int k = 0; k < 11; ++k) gw[k] = GW[k];

    // ---- stage A: horizontal 11-tap pass, global -> regs -> fp16 pairs in LDS
    // item = (row r of 42, x-quad q of 16): outputs cols gx0+4q..4q+3 for row gy0-5+r
    for (int it = tid; it < IN_H * 16; it += 256) {
        const int r = it >> 4;
        const int q = it & 15;
        const int gy = gy0 - HALO + r;
        const int c0 = gx0 + q * 4 - 8;              // 16B-aligned window base
        const bool rv = ((unsigned)gy < (unsigned)WSZ);
        const float* prow = Pp + (size_t)gy * WSZ;
        const float* trow = Tp + (size_t)gy * WSZ;

        float p[20], t[20];
        #pragma unroll
        for (int b = 0; b < 5; ++b) {
            const int c = c0 + 4 * b;
            float4 pv = make_float4(0.f, 0.f, 0.f, 0.f);
            float4 tv = make_float4(0.f, 0.f, 0.f, 0.f);
            if (rv && ((unsigned)c < (unsigned)WSZ)) {   // whole 4-px block in [0,512)
                pv = *(const float4*)(prow + c);
                tv = *(const float4*)(trow + c);
            }
            p[4*b+0] = pv.x; p[4*b+1] = pv.y; p[4*b+2] = pv.z; p[4*b+3] = pv.w;
            t[4*b+0] = tv.x; t[4*b+1] = tv.y; t[4*b+2] = tv.z; t[4*b+3] = tv.w;
        }

        float aP[4]  = {0.f,0.f,0.f,0.f};
        float aT[4]  = {0.f,0.f,0.f,0.f};
        float aPP[4] = {0.f,0.f,0.f,0.f};
        float aTT[4] = {0.f,0.f,0.f,0.f};
        float aPT[4] = {0.f,0.f,0.f,0.f};
        #pragma unroll
        for (int jj = 0; jj < 14; ++jj) {            // window px index jj+3
            const float pv = p[jj + 3];
            const float tv = t[jj + 3];
            const float pp = pv * pv, tt2 = tv * tv, pt = pv * tv;
            #pragma unroll
            for (int o = 0; o < 4; ++o) {
                const int k = jj - o;
                if (k >= 0 && k < 11) {
                    const float w = gw[k];
                    aP[o]  = fmaf(w, pv,  aP[o]);
                    aT[o]  = fmaf(w, tv,  aT[o]);
                    aPP[o] = fmaf(w, pp,  aPP[o]);
                    aTT[o] = fmaf(w, tt2, aTT[o]);
                    aPT[o] = fmaf(w, pt,  aPT[o]);
                }
            }
        }

        const int base = r * HPW + q * 2;            // even -> 8B-aligned b64 writes
        float2 v;
        v.x = pkh2(aP[0],  aP[1]);  v.y = pkh2(aP[2],  aP[3]);  *(float2*)&sHP[0*FS + base] = v;
        v.x = pkh2(aT[0],  aT[1]);  v.y = pkh2(aT[2],  aT[3]);  *(float2*)&sHP[1*FS + base] = v;
        v.x = pkh2(aPP[0], aPP[1]); v.y = pkh2(aPP[2], aPP[3]); *(float2*)&sHP[2*FS + base] = v;
        v.x = pkh2(aTT[0], aTT[1]); v.y = pkh2(aTT[2], aTT[3]); *(float2*)&sHP[3*FS + base] = v;
        v.x = pkh2(aPT[0], aPT[1]); v.y = pkh2(aPT[2], aPT[3]); *(float2*)&sHP[4*FS + base] = v;
    }
    __syncthreads();

    // ---- stage B: vertical 11-tap (packed fp16), MSE, SSIM ----
    // thread = (x-pair q2 of 32) x (4 rows y0..y0+3); bank = q2 -> 2-way max (free)
    const int q2 = tid & 31;
    const int yq = tid >> 5;
    const int y0 = yq * 4;

    float mse = 0.f;
    {
        const float* pr = Pp + (size_t)(gy0 + y0) * WSZ + gx0 + 2 * q2;
        const float* tr = Tp + (size_t)(gy0 + y0) * WSZ + gx0 + 2 * q2;
        #pragma unroll
        for (int yo = 0; yo < 4; ++yo) {
            float2 pv = *(const float2*)(pr + yo * WSZ);
            float2 tv = *(const float2*)(tr + yo * WSZ);
            float d0 = pv.x - tv.x;
            float d1 = pv.y - tv.y;
            mse = fmaf(d0, d0, mse);
            mse = fmaf(d1, d1, mse);
        }
    }

    __half2 gwh[11];
    #pragma unroll
    for (int k = 0; k < 11; ++k) gwh[k] = __float2half2_rn(gw[k]);

    __half2 acc[4][5];
    #pragma unroll
    for (int yo = 0; yo < 4; ++yo)
        #pragma unroll
        for (int f = 0; f < 5; ++f)
            acc[yo][f] = __float2half2_rn(0.f);

    #pragma unroll
    for (int j = 0; j < 14; ++j) {                   // rows y0..y0+13 cover 4 outputs
        const int row = y0 + j;
        float hv[5];
        #pragma unroll
        for (int f = 0; f < 5; ++f) hv[f] = sHP[f*FS + row*HPW + q2];
        #pragma unroll
        for (int yo = 0; yo < 4; ++yo) {
            const int k = j - yo;
            if (k >= 0 && k < 11) {
                #pragma unroll
                for (int f = 0; f < 5; ++f)
                    acc[yo][f] = __hfma2(gwh[k], __builtin_bit_cast(__half2, hv[f]), acc[yo][f]);
            }
        }
    }

    float ssim = 0.f;
    #pragma unroll
    for (int yo = 0; yo < 4; ++yo) {
        float2 m1  = __half22float2(acc[yo][0]);
        float2 m2  = __half22float2(acc[yo][1]);
        float2 spp = __half22float2(acc[yo][2]);
        float2 stt = __half22float2(acc[yo][3]);
        float2 spt = __half22float2(acc[yo][4]);
        #pragma unroll
        for (int e = 0; e < 2; ++e) {
            const float mu1 = e ? m1.y  : m1.x;
            const float mu2 = e ? m2.y  : m2.x;
            const float vpp = e ? spp.y : spp.x;
            const float vtt = e ? stt.y : stt.x;
            const float vpt = e ? spt.y : spt.x;
            const float mu1sq = mu1 * mu1;
            const float mu2sq = mu2 * mu2;
            const float mu12  = mu1 * mu2;
            const float s1  = vpp - mu1sq;
            const float s2  = vtt - mu2sq;
            const float s12 = vpt - mu12;
            const float num = fmaf(2.f, mu12, SSIM_C1) * fmaf(2.f, s12, SSIM_C2);
            const float den = (mu1sq + mu2sq + SSIM_C1) * (s1 + s2 + SSIM_C2);
            ssim = fmaf(num, __builtin_amdgcn_rcpf(den), ssim);
        }
    }

    // ---- reduction + last-block finalize ----
    #pragma unroll
    for (int off = 32; off > 0; off >>= 1) {
        mse  += __shfl_down(mse, off);
        ssim += __shfl_down(ssim, off);
    }
    const int wid = tid >> 6;
    if ((tid & 63) == 0) { red[0][wid] = mse; red[1][wid] = ssim; }
    __syncthreads();
    if (tid == 0) {
        const float m = red[0][0] + red[0][1] + red[0][2] + red[0][3];
        const float s = red[1][0] + red[1][1] + red[1][2] + red[1][3];
        atomicAdd(&ws[0], m);
        atomicAdd(&ws[1], s);
        __threadfence();
        const unsigned old = atomicAdd((unsigned*)&ws[2], 1u);
        if (old == (unsigned)(nblk - 1)) {
            const float tm = __hip_atomic_load(&ws[0], __ATOMIC_RELAXED, __HIP_MEMORY_SCOPE_AGENT);
            const float ts = __hip_atomic_load(&ws[1], __ATOMIC_RELAXED, __HIP_MEMORY_SCOPE_AGENT);
            out[0] = tm * invN + 0.01f * (1.f - ts * invN);
        }
    }
}

extern "C" void kernel_launch(void* const* d_in, const int* in_sizes, int n_in,
                              void* d_out, int out_size, void* d_ws, size_t ws_size,
                              hipStream_t stream) {
    const float* P = (const float*)d_in[0];
    const float* T = (const float*)d_in[1];
    float* out = (float*)d_out;
    float* ws  = (float*)d_ws;

    const int planes = in_sizes[0] / (WSZ * WSZ);     // 96
    const float invN = 1.f / (float)in_sizes[0];
    const int nblk = GX * GY * planes;

    (void)hipMemsetAsync(ws, 0, 3 * sizeof(float), stream);
    dim3 grid(GX, GY, planes);
    fused_mse_ssim<<<grid, 256, 0, stream>>>(P, T, out, ws, invN, nblk);
}

// Round 4
// 264.148 us; speedup vs baseline: 2.8932x; 2.8932x over previous
//
#include <hip/hip_runtime.h>
#include <hip/hip_fp16.h>

// Fused MSE + SSIM loss, 32x3x512x512 fp32, MI355X.
// R4: 64x16 tile, 16.6KB LDS (4 fields packed in float4 slots + 1 b32 field),
// launch_bounds(256,8) -> 8 blocks/CU (32 waves), MSE folded into stage A,
// 64-slot spread atomics + separate finalize kernel.

#define WSZ   512
#define TW    64
#define TH    16
#define HALO  5
#define IN_H  (TH + 2*HALO)    // 26 rows of horizontal-pass output
#define NPOS  32               // half2 positions per row (64 px)
#define GX    (WSZ / TW)       // 8
#define GY    (WSZ / TH)       // 32
#define NSLOT 64               // atomic accumulator slots (64B apart)
#define SSIM_C1 0.0001f
#define SSIM_C2 0.0009f

// 11-tap gaussian, sigma=1.5, normalized
#define W0 0.00102838f
#define W1 0.00759876f
#define W2 0.03600080f
#define W3 0.10936080f
#define W4 0.21300560f
#define W5 0.26601170f
__device__ __constant__ const float GW[11] = {W0,W1,W2,W3,W4,W5,W4,W3,W2,W1,W0};

// v_cvt_pkrtz_f16_f32: two fp32 -> packed fp16x2
static __device__ __forceinline__ float pkh2(float a, float b) {
    return __builtin_bit_cast(float, __builtin_amdgcn_cvt_pkrtz(a, b));
}

__launch_bounds__(256, 8)
__global__ void fused_mse_ssim(const float* __restrict__ P,
                               const float* __restrict__ T,
                               float* __restrict__ ws) {
    __shared__ float4 sAB[IN_H][NPOS];   // fields: P, T, PP, TT (half2 each)
    __shared__ float  sC [IN_H][NPOS];   // field PT (half2)
    __shared__ float  red[2][4];

    const int tid = threadIdx.x;
    const int gx0 = blockIdx.x * TW;
    const int gy0 = blockIdx.y * TH;
    const size_t plane = (size_t)blockIdx.z * (WSZ * (size_t)WSZ);
    const float* Pp = P + plane;
    const float* Tp = T + plane;

    float gw[11];
    #pragma unroll
    for (int k = 0; k < 11; ++k) gw[k] = GW[k];

    float mse = 0.f;

    // ---- stage A: horizontal 11-tap pass (global -> regs -> LDS fp16), MSE folded in
    for (int it = tid; it < IN_H * 16; it += 256) {   // 416 items
        const int r = it >> 4;
        const int q = it & 15;
        const int gy = gy0 - HALO + r;
        const int c0 = gx0 + q * 4 - 8;               // 16B-aligned window base
        const bool rv = ((unsigned)gy < (unsigned)WSZ);
        const float* prow = Pp + (size_t)gy * WSZ;
        const float* trow = Tp + (size_t)gy * WSZ;

        float p[20], t[20];
        #pragma unroll
        for (int b = 0; b < 5; ++b) {
            const int c = c0 + 4 * b;
            float4 pv = make_float4(0.f, 0.f, 0.f, 0.f);
            float4 tv = make_float4(0.f, 0.f, 0.f, 0.f);
            if (rv && ((unsigned)c < (unsigned)WSZ)) {
                pv = *(const float4*)(prow + c);
                tv = *(const float4*)(trow + c);
            }
            p[4*b+0] = pv.x; p[4*b+1] = pv.y; p[4*b+2] = pv.z; p[4*b+3] = pv.w;
            t[4*b+0] = tv.x; t[4*b+1] = tv.y; t[4*b+2] = tv.z; t[4*b+3] = tv.w;
        }

        // MSE: tile pixels of this item are window indices 8..11 (interior rows only)
        if ((unsigned)(r - HALO) < (unsigned)TH) {
            #pragma unroll
            for (int i = 0; i < 4; ++i) {
                const float d = p[8 + i] - t[8 + i];
                mse = fmaf(d, d, mse);
            }
        }

        float aP[4]  = {0.f,0.f,0.f,0.f};
        float aT[4]  = {0.f,0.f,0.f,0.f};
        float aPP[4] = {0.f,0.f,0.f,0.f};
        float aTT[4] = {0.f,0.f,0.f,0.f};
        float aPT[4] = {0.f,0.f,0.f,0.f};
        #pragma unroll
        for (int jj = 0; jj < 14; ++jj) {
            const float pv = p[jj + 3];
            const float tv = t[jj + 3];
            const float pp = pv * pv, tt2 = tv * tv, pt = pv * tv;
            #pragma unroll
            for (int o = 0; o < 4; ++o) {
                const int k = jj - o;
                if (k >= 0 && k < 11) {
                    const float w = gw[k];
                    aP[o]  = fmaf(w, pv,  aP[o]);
                    aT[o]  = fmaf(w, tv,  aT[o]);
                    aPP[o] = fmaf(w, pp,  aPP[o]);
                    aTT[o] = fmaf(w, tt2, aTT[o]);
                    aPT[o] = fmaf(w, pt,  aPT[o]);
                }
            }
        }

        sAB[r][2*q]   = make_float4(pkh2(aP[0], aP[1]), pkh2(aT[0], aT[1]),
                                    pkh2(aPP[0],aPP[1]), pkh2(aTT[0],aTT[1]));
        sAB[r][2*q+1] = make_float4(pkh2(aP[2], aP[3]), pkh2(aT[2], aT[3]),
                                    pkh2(aPP[2],aPP[3]), pkh2(aTT[2],aTT[3]));
        sC [r][2*q]   = pkh2(aPT[0], aPT[1]);
        sC [r][2*q+1] = pkh2(aPT[2], aPT[3]);
    }
    __syncthreads();

    // ---- stage B: vertical 11-tap (packed fp16) + SSIM ----
    // thread = (half2 col q2 of 32) x (2 rows y0, y0+1); b128 stride-16B reads: conflict-free
    __half2 gwh[11];
    #pragma unroll
    for (int k = 0; k < 11; ++k) gwh[k] = __float2half2_rn(gw[k]);

    const int q2 = tid & 31;
    const int y0 = (tid >> 5) * 2;      // 0,2,..,14

    __half2 acc[2][5];
    #pragma unroll
    for (int a = 0; a < 2; ++a)
        #pragma unroll
        for (int f = 0; f < 5; ++f)
            acc[a][f] = __float2half2_rn(0.f);

    #pragma unroll
    for (int j = 0; j < 12; ++j) {      // window rows y0..y0+11 cover both outputs
        const float4 ab = sAB[y0 + j][q2];
        const float  cc = sC [y0 + j][q2];
        __half2 h[5];
        h[0] = __builtin_bit_cast(__half2, ab.x);
        h[1] = __builtin_bit_cast(__half2, ab.y);
        h[2] = __builtin_bit_cast(__half2, ab.z);
        h[3] = __builtin_bit_cast(__half2, ab.w);
        h[4] = __builtin_bit_cast(__half2, cc);
        if (j < 11) {
            #pragma unroll
            for (int f = 0; f < 5; ++f) acc[0][f] = __hfma2(gwh[j], h[f], acc[0][f]);
        }
        if (j >= 1) {
            #pragma unroll
            for (int f = 0; f < 5; ++f) acc[1][f] = __hfma2(gwh[j-1], h[f], acc[1][f]);
        }
    }

    float ssim = 0.f;
    #pragma unroll
    for (int a = 0; a < 2; ++a) {
        const float2 m1  = __half22float2(acc[a][0]);
        const float2 m2  = __half22float2(acc[a][1]);
        const float2 spp = __half22float2(acc[a][2]);
        const float2 stt = __half22float2(acc[a][3]);
        const float2 spt = __half22float2(acc[a][4]);
        #pragma unroll
        for (int e = 0; e < 2; ++e) {
            const float mu1 = e ? m1.y  : m1.x;
            const float mu2 = e ? m2.y  : m2.x;
            const float vpp = e ? spp.y : spp.x;
            const float vtt = e ? stt.y : stt.x;
            const float vpt = e ? spt.y : spt.x;
            const float mu1sq = mu1 * mu1;
            const float mu2sq = mu2 * mu2;
            const float mu12  = mu1 * mu2;
            const float s1  = vpp - mu1sq;
            const float s2  = vtt - mu2sq;
            const float s12 = vpt - mu12;
            const float num = fmaf(2.f, mu12, SSIM_C1) * fmaf(2.f, s12, SSIM_C2);
            const float den = (mu1sq + mu2sq + SSIM_C1) * (s1 + s2 + SSIM_C2);
            ssim = fmaf(num, __builtin_amdgcn_rcpf(den), ssim);
        }
    }

    // ---- reduction: wave shuffle -> LDS -> 2 atomics into a spread slot ----
    #pragma unroll
    for (int off = 32; off > 0; off >>= 1) {
        mse  += __shfl_down(mse, off);
        ssim += __shfl_down(ssim, off);
    }
    const int wid = tid >> 6;
    if ((tid & 63) == 0) { red[0][wid] = mse; red[1][wid] = ssim; }
    __syncthreads();
    if (tid == 0) {
        const float m = red[0][0] + red[0][1] + red[0][2] + red[0][3];
        const float s = red[1][0] + red[1][1] + red[1][2] + red[1][3];
        const int bid  = (blockIdx.z * gridDim.y + blockIdx.y) * gridDim.x + blockIdx.x;
        const int slot = (bid & (NSLOT - 1)) * 16;   // 64B apart -> no line bouncing
        atomicAdd(&ws[slot + 0], m);
        atomicAdd(&ws[slot + 1], s);
    }
}

__global__ void finalize_loss(const float* __restrict__ ws,
                              float* __restrict__ out, float invN) {
    const int t = threadIdx.x;           // 64 threads
    float m = ws[t * 16 + 0];
    float s = ws[t * 16 + 1];
    #pragma unroll
    for (int off = 32; off > 0; off >>= 1) {
        m += __shfl_down(m, off);
        s += __shfl_down(s, off);
    }
    if (t == 0) out[0] = m * invN + 0.01f * (1.f - s * invN);
}

extern "C" void kernel_launch(void* const* d_in, const int* in_sizes, int n_in,
                              void* d_out, int out_size, void* d_ws, size_t ws_size,
                              hipStream_t stream) {
    const float* P = (const float*)d_in[0];
    const float* T = (const float*)d_in[1];
    float* out = (float*)d_out;
    float* ws  = (float*)d_ws;

    const int planes = in_sizes[0] / (WSZ * WSZ);     // 96
    const float invN = 1.f / (float)in_sizes[0];

    (void)hipMemsetAsync(ws, 0, NSLOT * 16 * sizeof(float), stream);
    dim3 grid(GX, GY, planes);
    fused_mse_ssim<<<grid, 256, 0, stream>>>(P, T, ws);
    finalize_loss<<<1, 64, 0, stream>>>(ws, out, invN);
}